// Round 3
// baseline (333.206 us; speedup 1.0000x reference)
//
#include <hip/hip_runtime.h>
#include <cstdint>
#include <cstddef>

// ---------------- problem constants ----------------
#define HW 36864            // 192*192
#define KS 16               // K-split slices
#define SLICE (HW / KS)     // 2304
#define NCHUNK (SLICE / 64) // 36
#define QT 16               // queries per tile

// valid stereographic pixels: z>0  <=>  (2u-63)^2 + (2v-63)^2 < 1024 (integer-exact;
// odd^2+odd^2 == 1024 is impossible mod 8, so the boundary is never hit)
constexpr bool is_valid_px(int v, int u) {
  int a = 2 * u - 63, b = 2 * v - 63;
  return a * a + b * b < 1024;
}
constexpr int count_valid() {
  int n = 0;
  for (int v = 0; v < 64; ++v)
    for (int u = 0; u < 64; ++u)
      if (is_valid_px(v, u)) ++n;
  return n;
}
constexpr int NV  = count_valid();          // 812
constexpr int NQT = (NV + QT - 1) / QT;     // 51 tiles of 16
constexpr int NQP = NQT * QT;               // 816 padded queries

struct QTab {
  short idx[NQP];    // rank -> pixel (or -1 pad)
  short rank[4096];  // pixel -> rank (or -1 invalid)
};
constexpr QTab make_qtab() {
  QTab t{};
  int n = 0;
  for (int p = 0; p < 4096; ++p) {
    int v = p >> 6, u = p & 63;
    if (is_valid_px(v, u)) { t.idx[n] = (short)p; t.rank[p] = (short)n; ++n; }
    else t.rank[p] = -1;
  }
  for (int i = n; i < NQP; ++i) t.idx[i] = -1;
  return t;
}
__constant__ QTab g_qtab = make_qtab();

// partial layout: part[ ((b*NQP + q)*72 + ch) * KS + ks ]
//   ch 0..63 : sum w*fea_c      ch 64..66 : sum w*fea_{61..63}^2
//   ch 67    : sum w*cos        ch 68     : sum w

__global__ __launch_bounds__(256) void partial_kernel(
    const float* __restrict__ fea,
    const float* __restrict__ nrm,
    const float* __restrict__ msk,
    const float* __restrict__ lqn,
    float* __restrict__ part)
{
  __shared__ float fea_s[64][68];   // [channel][pixel]
  __shared__ float w_s[QT][68];     // [query][pixel]
  __shared__ float nrm_s[3][64];
  __shared__ float mask_s[64];
  __shared__ float qn_s[QT][4];

  const int blk = blockIdx.x;
  const int ks  = blk % KS;
  const int qt  = (blk / KS) % NQT;
  const int b   = blk / (KS * NQT);

  const int t  = threadIdx.x;
  const int tc = t & 63;   // channel lane
  const int tq = t >> 6;   // query group (wave id)

  const float s  = __expf(lqn[0]);
  const float Cc = s * 0.57735026919f;   // s/sqrt(3); w = exp(Cc*(cos-1))

  if (t < QT) {
    int pix = g_qtab.idx[qt * QT + t];
    float x = 0.f, y = 0.f, z = 0.f;
    if (pix >= 0) {
      int v = pix >> 6, u = pix & 63;
      float p = (float)(2 * u - 63) * (1.0f / 32.0f);
      float q = -(float)(2 * v - 63) * (1.0f / 32.0f);
      float d = 1.0f + p * p + q * q;
      x = 2.0f * p / d; y = 2.0f * q / d; z = (1.0f - p * p - q * q) / d;
    }
    qn_s[t][0] = x; qn_s[t][1] = y; qn_s[t][2] = z; qn_s[t][3] = 0.f;
  }
  __syncthreads();

  float qx[4], qy[4], qz[4];
  #pragma unroll
  for (int i = 0; i < 4; ++i) {
    qx[i] = qn_s[4 * tq + i][0];
    qy[i] = qn_s[4 * tq + i][1];
    qz[i] = qn_s[4 * tq + i][2];
  }

  float accf[4] = {0.f, 0.f, 0.f, 0.f};   // (q = 4*tq+i, ch = tc)
  float asw[4]  = {0.f, 0.f, 0.f, 0.f};
  float aswc[4] = {0.f, 0.f, 0.f, 0.f};
  float asq[4][3] = {};

  const size_t base_f = (size_t)b * 64 * HW;
  const size_t base_n = (size_t)b * 3 * HW;
  const size_t base_m = (size_t)b * HW;
  int m0 = ks * SLICE;

  for (int ck = 0; ck < NCHUNK; ++ck, m0 += 64) {
    // ---- stage: fea chunk (64 px x 64 ch) + normals + mask (f32 inputs) ----
    {
      const int px4 = (t & 15) * 4;
      const int chb = t >> 4;
      #pragma unroll
      for (int i = 0; i < 4; ++i) {
        int ch = chb + 16 * i;
        const float* p = fea + base_f + (size_t)ch * HW + (size_t)(m0 + px4);
        float4 fv = *(const float4*)p;
        *(float4*)&fea_s[ch][px4] = fv;
      }
      const int arr = t >> 6;
      const int px  = t & 63;
      if (arr < 3) nrm_s[arr][px] = nrm[base_n + (size_t)arr * HW + (size_t)(m0 + px)];
      else         mask_s[px]     = msk[base_m + (size_t)(m0 + px)];
    }
    __syncthreads();

    // ---- w phase: w[16q][64px] + extra accumulators ----
    {
      const int px = tc;
      float nx = nrm_s[0][px], ny = nrm_s[1][px], nz = nrm_s[2][px];
      float mk = mask_s[px];
      float v0 = fea_s[61][px], v1 = fea_s[62][px], v2 = fea_s[63][px];
      float s0 = v0 * v0, s1 = v1 * v1, s2 = v2 * v2;
      #pragma unroll
      for (int i = 0; i < 4; ++i) {
        float c = qx[i] * nx + qy[i] * ny + qz[i] * nz;
        float e = __expf(Cc * (c - 1.0f)) * mk;
        w_s[4 * tq + i][px] = e;
        asw[i]    += e;
        aswc[i]   += e * c;
        asq[i][0] += e * s0;
        asq[i][1] += e * s1;
        asq[i][2] += e * s2;
      }
    }
    __syncthreads();   // w_s visible to compute phase

    // ---- compute phase: acc[q][tc] += sum_px w[q][px] * fea[tc][px] ----
    #pragma unroll 4
    for (int p0 = 0; p0 < 64; p0 += 4) {
      float4 v4 = *(const float4*)&fea_s[tc][p0];
      #pragma unroll
      for (int i = 0; i < 4; ++i) {
        float4 w4 = *(const float4*)&w_s[4 * tq + i][p0];  // wave-broadcast
        accf[i] += v4.x * w4.x;
        accf[i] += v4.y * w4.y;
        accf[i] += v4.z * w4.z;
        accf[i] += v4.w * w4.w;
      }
    }
    __syncthreads();
  }

  // ---- write fea partials: one owner thread per (q, ch) ----
  #pragma unroll
  for (int i = 0; i < 4; ++i) {
    size_t q = (size_t)b * NQP + (size_t)(qt * QT + 4 * tq + i);
    part[(q * 72 + (size_t)tc) * KS + ks] = accf[i];
  }
  // ---- wave-reduce extras (64 px lanes per wave) ----
  #pragma unroll
  for (int i = 0; i < 4; ++i) {
    float vsw = asw[i], vswc = aswc[i];
    float v0 = asq[i][0], v1 = asq[i][1], v2 = asq[i][2];
    #pragma unroll
    for (int off = 32; off > 0; off >>= 1) {
      vsw  += __shfl_xor(vsw, off);
      vswc += __shfl_xor(vswc, off);
      v0   += __shfl_xor(v0, off);
      v1   += __shfl_xor(v1, off);
      v2   += __shfl_xor(v2, off);
    }
    if (tc == 0) {
      size_t q = (size_t)b * NQP + (size_t)(qt * QT + 4 * tq + i);
      part[(q * 72 + 64) * KS + ks] = v0;
      part[(q * 72 + 65) * KS + ks] = v1;
      part[(q * 72 + 66) * KS + ks] = v2;
      part[(q * 72 + 67) * KS + ks] = vswc;
      part[(q * 72 + 68) * KS + ks] = vsw;
    }
  }
}

__global__ __launch_bounds__(128) void combine_kernel(
    const float* __restrict__ part,
    float* __restrict__ out)              // reference output dtype = float32
{
  const int blk = blockIdx.x;
  const int pix = blk & 4095;
  const int b   = blk >> 12;
  const int t   = threadIdx.x;
  const int rank = g_qtab.rank[pix];

  if (rank < 0) {                       // whole block uniform -> safe early exit
    if (t < 69) out[(size_t)(b * 69 + t) * 4096 + pix] = 0.0f;
    return;
  }

  __shared__ float pv[69];
  if (t < 69) {
    const float* p = part + (((size_t)b * NQP + (size_t)rank) * 72 + (size_t)t) * KS;
    float s = 0.f;
    #pragma unroll
    for (int k = 0; k < KS; ++k) s += p[k];
    pv[t] = s;
  }
  __syncthreads();

  const float inv = 1.0f / (pv[68] + 1e-9f);
  float val = 0.f;
  if (t == 0) {
    val = pv[67] * inv;                          // rm_cos
  } else if (t == 1) {                           // var
    #pragma unroll
    for (int i = 0; i < 3; ++i) {
      float m  = pv[61 + i] * inv;
      float sq = pv[64 + i] * inv;
      val += sq - m * m;
    }
  } else if (t < 5) {                            // qn
    int v = pix >> 6, u = pix & 63;
    float p = (float)(2 * u - 63) * (1.0f / 32.0f);
    float q = -(float)(2 * v - 63) * (1.0f / 32.0f);
    float d = 1.0f + p * p + q * q;
    float qn0 = 2.0f * p / d, qn1 = 2.0f * q / d, qn2 = (1.0f - p * p - q * q) / d;
    val = (t == 2) ? qn0 : (t == 3) ? qn1 : qn2;
  } else if (t < 69) {                           // mapped features
    val = pv[t - 5] * inv;
  }
  if (t < 69) out[(size_t)(b * 69 + t) * 4096 + pix] = val;
}

extern "C" void kernel_launch(void* const* d_in, const int* in_sizes, int n_in,
                              void* d_out, int out_size, void* d_ws, size_t ws_size,
                              hipStream_t stream) {
  const float* fea = (const float*)d_in[0];
  const float* nrm = (const float*)d_in[1];
  const float* msk = (const float*)d_in[2];
  const float* lqn = (const float*)d_in[3];
  float* part = (float*)d_ws;            // 2*816*72*16*4 B = 7.52 MB; every read slot
                                         // is rewritten each launch -> no memset needed
  float* out = (float*)d_out;

  dim3 grid1(2 * NQT * KS);              // 1632 blocks
  partial_kernel<<<grid1, 256, 0, stream>>>(fea, nrm, msk, lqn, part);
  combine_kernel<<<dim3(2 * 4096), 128, 0, stream>>>(part, out);
}

// Round 4
// 178.258 us; speedup vs baseline: 1.8692x; 1.8692x over previous
//
#include <hip/hip_runtime.h>
#include <cstdint>
#include <cstddef>

// ---------------- problem constants ----------------
#define HW 36864            // 192*192
#define KS 16               // K-split slices
#define SLICE (HW / KS)     // 2304
#define NCHUNK (SLICE / 64) // 36
#define QT 64               // queries per tile (M-tile)

constexpr bool is_valid_px(int v, int u) {
  int a = 2 * u - 63, b = 2 * v - 63;
  return a * a + b * b < 1024;   // integer-exact (==1024 impossible for odd,odd)
}
constexpr int count_valid() {
  int n = 0;
  for (int v = 0; v < 64; ++v)
    for (int u = 0; u < 64; ++u)
      if (is_valid_px(v, u)) ++n;
  return n;
}
constexpr int NV  = count_valid();          // 812
constexpr int NQT = (NV + QT - 1) / QT;     // 13 tiles of 64
constexpr int NQP = NQT * QT;               // 832 padded queries

struct QTab {
  short idx[NQP];    // rank -> pixel (or -1 pad)
};
constexpr QTab make_qtab() {
  QTab t{};
  int n = 0;
  for (int p = 0; p < 4096; ++p) {
    int v = p >> 6, u = p & 63;
    if (is_valid_px(v, u)) { t.idx[n] = (short)p; ++n; }
  }
  for (int i = n; i < NQP; ++i) t.idx[i] = -1;
  return t;
}
__constant__ QTab g_qtab = make_qtab();

typedef short short8 __attribute__((ext_vector_type(8)));
typedef float f32x4  __attribute__((ext_vector_type(4)));

__device__ __forceinline__ unsigned short f2b(float f) {  // f32 -> bf16 RNE
  unsigned int u = __float_as_uint(f);
  u += 0x7FFFu + ((u >> 16) & 1u);
  return (unsigned short)(u >> 16);
}
__device__ __forceinline__ ushort4 f2b4(float4 v) {
  ushort4 r; r.x = f2b(v.x); r.y = f2b(v.y); r.z = f2b(v.z); r.w = f2b(v.w);
  return r;
}

// partial layout: part[ ((b*NQP + q)*69 + ch) * KS + ks ]
//   ch 0..63 : sum w*fea_c   64..66 : sum w*fea_{61..63}^2   67 : sum w*cos   68 : sum w

__global__ __launch_bounds__(256) void partial_kernel(
    const float* __restrict__ fea,
    const float* __restrict__ nrm,
    const float* __restrict__ msk,
    const float* __restrict__ lqn,
    float* __restrict__ part)
{
  // LDS: B-tile v_s rows: 0..63 fea, 64..66 fea^2(61..63), 67..69 nrm, 70 ones, 71..79 zero
  __shared__ __align__(16) unsigned short v_s[80][72];  // 11520 B, +8 pad (2-way free)
  __shared__ __align__(16) unsigned short w_s[64][72];  // 9216 B
  __shared__ float nrm_s[3][64];
  __shared__ float mask_s[64];
  __shared__ float qn_s[64][4];
  __shared__ float ex_s[64][8];

  // XCD-swizzled decode: blocks with equal (b,ks) share blockIdx%8 -> same-XCD L2 reuse
  const int bx   = blockIdx.x;        // 0..415
  const int cls  = bx & 7;
  const int s_   = bx >> 3;           // 0..51
  const int gset = s_ / NQT;          // 0..3
  const int qt   = s_ % NQT;          // 0..12
  const int g    = gset * 8 + cls;    // 0..31
  const int b    = g >> 4;
  const int ks   = g & 15;

  const int t    = threadIdx.x;
  const int wv   = t >> 6;            // wave 0..3 -> M-tile rows 16*wv..16*wv+15
  const int l    = t & 63;

  const float sh = __expf(lqn[0]);
  const float Cc = sh * 0.57735026919f;   // s/sqrt(3); w = exp(Cc*(cos-1))

  // ---- one-time init ----
  if (t < 64) {
    int pix = g_qtab.idx[qt * QT + t];
    float x = 0.f, y = 0.f, z = 0.f;
    if (pix >= 0) {
      int v = pix >> 6, u = pix & 63;
      float p = (float)(2 * u - 63) * (1.0f / 32.0f);
      float q = -(float)(2 * v - 63) * (1.0f / 32.0f);
      float d = 1.0f + p * p + q * q;
      x = 2.0f * p / d; y = 2.0f * q / d; z = (1.0f - p * p - q * q) / d;
    }
    qn_s[t][0] = x; qn_s[t][1] = y; qn_s[t][2] = z; qn_s[t][3] = 0.f;
  }
  if (t < 160) {                      // rows 70..79: ones then zeros (constant all chunks)
    int row = 70 + (t >> 4);
    int px4 = (t & 15) * 4;
    unsigned short c = (row == 70) ? (unsigned short)0x3F80 : (unsigned short)0;
    ushort4 val; val.x = c; val.y = c; val.z = c; val.w = c;
    *(ushort4*)&v_s[row][px4] = val;
  }
  __syncthreads();

  // per-wave query direction registers (16 q per wave)
  float qx[16], qy[16], qz[16];
  #pragma unroll
  for (int i = 0; i < 16; ++i) {
    qx[i] = qn_s[16 * wv + i][0];
    qy[i] = qn_s[16 * wv + i][1];
    qz[i] = qn_s[16 * wv + i][2];
  }

  f32x4 acc[5];
  #pragma unroll
  for (int nt = 0; nt < 5; ++nt) acc[nt] = (f32x4)(0.0f);

  const size_t base_f = (size_t)b * 64 * HW;
  const size_t base_n = (size_t)b * 3 * HW;
  const size_t base_m = (size_t)b * HW;
  int m0 = ks * SLICE;

  const int mrow = l & 15;
  const int ko8  = (l >> 4) * 8;

  for (int ck = 0; ck < NCHUNK; ++ck, m0 += 64) {
    // ---- stage: fea chunk -> v_s bf16 (+ squares rows), normals + mask ----
    {
      const int px4 = (t & 15) * 4;
      const int chb = t >> 4;
      #pragma unroll
      for (int i = 0; i < 4; ++i) {
        int ch = chb + 16 * i;
        float4 fv = *(const float4*)(fea + base_f + (size_t)ch * HW + (size_t)(m0 + px4));
        *(ushort4*)&v_s[ch][px4] = f2b4(fv);
        if (ch >= 61) {
          float4 sq = make_float4(fv.x * fv.x, fv.y * fv.y, fv.z * fv.z, fv.w * fv.w);
          *(ushort4*)&v_s[ch + 3][px4] = f2b4(sq);
        }
      }
      if (t < 192) {
        int arr = t >> 6, px = t & 63;
        float f = nrm[base_n + (size_t)arr * HW + (size_t)(m0 + px)];
        nrm_s[arr][px] = f;
        v_s[67 + arr][px] = f2b(f);
      } else {
        int px = t & 63;
        mask_s[px] = msk[base_m + (size_t)(m0 + px)];
      }
    }
    __syncthreads();

    // ---- w phase: each wave computes its 16 queries for px = lane ----
    {
      const int px = l;
      float nx = nrm_s[0][px], ny = nrm_s[1][px], nz = nrm_s[2][px];
      float mk = mask_s[px];
      #pragma unroll
      for (int i = 0; i < 16; ++i) {
        float c = qx[i] * nx + qy[i] * ny + qz[i] * nz;
        float e = __expf(Cc * (c - 1.0f)) * mk;
        w_s[16 * wv + i][px] = f2b(e);
      }
    }
    __syncthreads();

    // ---- MFMA: D[64q x 80ch] += W[64q x 64px] * V'[64px x 80ch] ----
    #pragma unroll
    for (int kk = 0; kk < 64; kk += 32) {
      short8 a = *(const short8*)&w_s[16 * wv + mrow][kk + ko8];
      #pragma unroll
      for (int nt = 0; nt < 5; ++nt) {
        short8 bb = *(const short8*)&v_s[16 * nt + mrow][kk + ko8];
        acc[nt] = __builtin_amdgcn_mfma_f32_16x16x32_bf16(a, bb, acc[nt], 0, 0, 0);
      }
    }
    __syncthreads();   // protect v_s/w_s before next chunk's staging
  }

  // ---- epilogue: C layout col=lane&15, row=(lane>>4)*4+reg ----
  #pragma unroll
  for (int nt = 0; nt < 4; ++nt) {
    #pragma unroll
    for (int r = 0; r < 4; ++r) {
      int q  = qt * QT + 16 * wv + (l >> 4) * 4 + r;
      int ch = 16 * nt + mrow;
      part[(((size_t)b * NQP + q) * 69 + ch) * KS + ks] = acc[nt][r];
    }
  }
  if (mrow < 7) {
    #pragma unroll
    for (int r = 0; r < 4; ++r)
      ex_s[16 * wv + (l >> 4) * 4 + r][mrow] = acc[4][r];
  }
  __syncthreads();
  if (t < 64) {
    int ql = t;
    int q  = qt * QT + ql;
    float swc = qn_s[ql][0] * ex_s[ql][3] + qn_s[ql][1] * ex_s[ql][4]
              + qn_s[ql][2] * ex_s[ql][5];
    size_t base = (((size_t)b * NQP + q) * 69) * KS + ks;
    part[base + (size_t)64 * KS] = ex_s[ql][0];
    part[base + (size_t)65 * KS] = ex_s[ql][1];
    part[base + (size_t)66 * KS] = ex_s[ql][2];
    part[base + (size_t)67 * KS] = swc;
    part[base + (size_t)68 * KS] = ex_s[ql][6];
  }
}

// reduce over KS, normalize, scatter valid pixels (out pre-zeroed by memset)
__global__ __launch_bounds__(128) void reduce_scatter_kernel(
    const float* __restrict__ part,
    float* __restrict__ out)
{
  const int bq = blockIdx.x;          // b*NQP + q
  const int q  = bq % NQP;
  const int b  = bq / NQP;
  const int t  = threadIdx.x;

  const int pix = g_qtab.idx[q];
  if (pix < 0) return;                // pad query (uniform)

  __shared__ float pv[69];
  if (t < 69) {
    const float* p = part + ((size_t)bq * 69 + (size_t)t) * KS;
    float s = 0.f;
    #pragma unroll
    for (int k = 0; k < KS; ++k) s += p[k];
    pv[t] = s;
  }
  __syncthreads();

  const float inv = 1.0f / (pv[68] + 1e-9f);
  float val = 0.f;
  if (t == 0) {
    val = pv[67] * inv;                          // rm_cos
  } else if (t == 1) {                           // var
    #pragma unroll
    for (int i = 0; i < 3; ++i) {
      float m  = pv[61 + i] * inv;
      float sq = pv[64 + i] * inv;
      val += sq - m * m;
    }
  } else if (t < 5) {                            // qn
    int v = pix >> 6, u = pix & 63;
    float p = (float)(2 * u - 63) * (1.0f / 32.0f);
    float q2 = -(float)(2 * v - 63) * (1.0f / 32.0f);
    float d = 1.0f + p * p + q2 * q2;
    float qn0 = 2.0f * p / d, qn1 = 2.0f * q2 / d, qn2 = (1.0f - p * p - q2 * q2) / d;
    val = (t == 2) ? qn0 : (t == 3) ? qn1 : qn2;
  } else if (t < 69) {                           // mapped features
    val = pv[t - 5] * inv;
  }
  if (t < 69) out[(size_t)(b * 69 + t) * 4096 + pix] = val;
}

extern "C" void kernel_launch(void* const* d_in, const int* in_sizes, int n_in,
                              void* d_out, int out_size, void* d_ws, size_t ws_size,
                              hipStream_t stream) {
  const float* fea = (const float*)d_in[0];
  const float* nrm = (const float*)d_in[1];
  const float* msk = (const float*)d_in[2];
  const float* lqn = (const float*)d_in[3];
  float* part = (float*)d_ws;   // 2*832*69*16*4 = 7.35 MB (< 7.52 MB proven OK);
                                // every slot rewritten each launch -> no memset needed
  float* out = (float*)d_out;

  hipMemsetAsync(d_out, 0, (size_t)out_size * sizeof(float), stream);
  partial_kernel<<<dim3(2 * NQT * KS), 256, 0, stream>>>(fea, nrm, msk, lqn, part);
  reduce_scatter_kernel<<<dim3(2 * NQP), 128, 0, stream>>>(part, out);
}

// Round 5
// 123.154 us; speedup vs baseline: 2.7056x; 1.4474x over previous
//
#include <hip/hip_runtime.h>
#include <cstdint>
#include <cstddef>

// ---------------- problem constants ----------------
#define HW 36864            // 192*192
#define QT 64               // queries per tile (M-tile)

constexpr bool is_valid_px(int v, int u) {
  int a = 2 * u - 63, b = 2 * v - 63;
  return a * a + b * b < 1024;   // integer-exact (==1024 impossible for odd,odd)
}
constexpr int count_valid() {
  int n = 0;
  for (int v = 0; v < 64; ++v)
    for (int u = 0; u < 64; ++u)
      if (is_valid_px(v, u)) ++n;
  return n;
}
constexpr int NV  = count_valid();          // 812
constexpr int NQT = (NV + QT - 1) / QT;     // 13 tiles of 64
constexpr int NQP = NQT * QT;               // 832 padded queries
constexpr int PLANE = 2 * NQP * 69;         // f32 elems per ks-plane of partials

struct QTab { short idx[NQP]; };            // rank -> pixel (or -1 pad)
constexpr QTab make_qtab() {
  QTab t{};
  int n = 0;
  for (int p = 0; p < 4096; ++p) {
    int v = p >> 6, u = p & 63;
    if (is_valid_px(v, u)) { t.idx[n] = (short)p; ++n; }
  }
  for (int i = n; i < NQP; ++i) t.idx[i] = -1;
  return t;
}
__constant__ QTab g_qtab = make_qtab();

typedef short short8 __attribute__((ext_vector_type(8)));
typedef float f32x4  __attribute__((ext_vector_type(4)));

__device__ __forceinline__ unsigned short f2b(float f) {  // f32 -> bf16 RNE
  unsigned int u = __float_as_uint(f);
  u += 0x7FFFu + ((u >> 16) & 1u);
  return (unsigned short)(u >> 16);
}
__device__ __forceinline__ ushort4 f2b4(float4 v) {
  ushort4 r; r.x = f2b(v.x); r.y = f2b(v.y); r.z = f2b(v.z); r.w = f2b(v.w);
  return r;
}
__device__ __forceinline__ void pix2qn(int pix, float& x, float& y, float& z) {
  x = 0.f; y = 0.f; z = 0.f;
  if (pix >= 0) {
    int v = pix >> 6, u = pix & 63;
    float p = (float)(2 * u - 63) * (1.0f / 32.0f);
    float q = -(float)(2 * v - 63) * (1.0f / 32.0f);
    float d = 1.0f + p * p + q * q;
    x = 2.0f * p / d; y = 2.0f * q / d; z = (1.0f - p * p - q * q) / d;
  }
}

// partial layout: part[ ks*PLANE + (b*NQP+q)*69 + ch ]  (block-contiguous writes)
//   ch 0..63 : sum w*fea_c   64..66 : sum w*fea_{61..63}^2   67 : sum w*cos   68 : sum w

template<int KSC>
__global__ __launch_bounds__(256) void partial_kernel(
    const float* __restrict__ fea,
    const float* __restrict__ nrm,
    const float* __restrict__ msk,
    const float* __restrict__ lqn,
    float* __restrict__ part)
{
  constexpr int SLICE  = HW / KSC;
  constexpr int NCHUNK = SLICE / 64;

  // B-tile rows: 0..63 fea, 64..66 fea^2(61..63), 67..69 nrm(raw), 70 ones, 71..79 zero
  __shared__ __align__(16) unsigned short v_s[2][80][72];  // 2x11520 B (2-way alias free)
  __shared__ __align__(16) float nrm4_s[2][64][4];         // permuted (Cc*n, bias)
  __shared__ float ex_s[64][9];

  // decode with XCD grouping: all 13 qt-blocks of a (b,ks) slice share blockIdx%8
  const int bx  = blockIdx.x;
  const int cls = bx & 7;
  const int r0  = bx >> 3;
  const int qt  = r0 % NQT;
  const int sh  = r0 / NQT;
  const int s   = sh * 8 + cls;       // slice id 0..2*KSC-1
  const int b   = s / KSC;
  const int ks  = s % KSC;

  const int t    = threadIdx.x;
  const int wv   = t >> 6;            // wave -> M rows 16wv..16wv+15
  const int l    = t & 63;
  const int lq   = l >> 4;            // k-quad
  const int mrow = l & 15;

  const float Cc = __expf(lqn[0]) * 0.57735026919f;   // s/sqrt(3); w = exp(Cc*(cos-1))

  // per-lane query geometry (A-frag row m = mrow)
  float qx, qy, qz;
  pix2qn(g_qtab.idx[qt * QT + 16 * wv + mrow], qx, qy, qz);

  // one-time const rows 70..79 in both buffers
  if (t < 160) {
    int row = 70 + (t >> 4);
    int p4  = (t & 15) * 4;
    unsigned short c = (row == 70) ? (unsigned short)0x3F80 : (unsigned short)0;
    ushort4 cv; cv.x = c; cv.y = c; cv.z = c; cv.w = c;
    *(ushort4*)&v_s[0][row][p4] = cv;
    *(ushort4*)&v_s[1][row][p4] = cv;
  }

  const size_t base_f = (size_t)b * 64 * HW;
  const size_t base_n = (size_t)b * 3 * HW;
  const size_t base_m = (size_t)b * HW;

  const int chb = t >> 4;             // staging channel base
  const int px4 = (t & 15) * 4;       // staging pixel offset
  const int arr = t >> 6;             // staging role: 0..2 nrm.xyz, 3 mask
  // bank-permuted px index: px' = 32*(px>>5) + 4*(px&7) + ((px>>3)&3)
  const int pxp = 32 * (l >> 5) + 4 * (l & 7) + ((l >> 3) & 3);

  f32x4 acc[5];
  #pragma unroll
  for (int nt = 0; nt < 5; ++nt) acc[nt] = (f32x4)(0.0f);

  float4 pf[4];
  float pn = 0.f, pm = 0.f;

  auto load_chunk = [&](int ck) {     // global -> registers (non-blocking)
    int m0 = ks * SLICE + ck * 64;
    #pragma unroll
    for (int i = 0; i < 4; ++i)
      pf[i] = *(const float4*)(fea + base_f + (size_t)(chb + 16 * i) * HW + (size_t)(m0 + px4));
    if (arr < 3) pn = nrm[base_n + (size_t)arr * HW + (size_t)(m0 + l)];
    else         pm = msk[base_m + (size_t)(m0 + l)];
  };
  auto store_chunk = [&](int buf) {   // registers -> LDS (bf16 + w-gen table)
    #pragma unroll
    for (int i = 0; i < 4; ++i) {
      int ch = chb + 16 * i;
      float4 fv = pf[i];
      *(ushort4*)&v_s[buf][ch][px4] = f2b4(fv);
      if (ch >= 61) {
        float4 sq = make_float4(fv.x * fv.x, fv.y * fv.y, fv.z * fv.z, fv.w * fv.w);
        *(ushort4*)&v_s[buf][ch + 3][px4] = f2b4(sq);
      }
    }
    if (arr < 3) {
      v_s[buf][67 + arr][l] = f2b(pn);        // raw nrm for sum(w*n) columns
      nrm4_s[buf][pxp][arr] = Cc * pn;        // premult for w-gen
    } else {
      // bias: -Cc (the cos-1 shift) + mask fold (exp(-2000+..) == 0.f exactly)
      nrm4_s[buf][pxp][3] = -Cc + (pm > 0.5f ? 0.f : -2000.f);
    }
  };

  load_chunk(0);
  store_chunk(0);
  __syncthreads();

  for (int ck = 0; ck < NCHUNK; ++ck) {
    const int buf = ck & 1;
    if (ck + 1 < NCHUNK) load_chunk(ck + 1);   // overlap w/ compute below

    #pragma unroll
    for (int kk = 0; kk < 64; kk += 32) {
      short8 a;
      #pragma unroll
      for (int j = 0; j < 8; ++j) {
        // px = kk + 8*lq + j  ->  permuted row kk + 4*j + lq (conflict-free b128)
        const float4 nv = *(const float4*)&nrm4_s[buf][kk + 4 * j + lq][0];
        float tt = fmaf(qx, nv.x, fmaf(qy, nv.y, fmaf(qz, nv.z, nv.w)));
        a[j] = (short)f2b(__expf(tt));
      }
      #pragma unroll
      for (int nt = 0; nt < 5; ++nt) {
        short8 bb = *(const short8*)&v_s[buf][16 * nt + mrow][kk + 8 * lq];
        acc[nt] = __builtin_amdgcn_mfma_f32_16x16x32_bf16(a, bb, acc[nt], 0, 0, 0);
      }
    }

    if (ck + 1 < NCHUNK) {
      store_chunk(buf ^ 1);
      __syncthreads();                 // single barrier per chunk
    }
  }

  // ---- epilogue: C layout col=lane&15, row=lq*4+reg ----
  const size_t pbase = (size_t)ks * PLANE + ((size_t)b * NQP + (size_t)(qt * QT)) * 69;
  #pragma unroll
  for (int nt = 0; nt < 4; ++nt) {
    #pragma unroll
    for (int rr = 0; rr < 4; ++rr) {
      int qloc = 16 * wv + 4 * lq + rr;
      part[pbase + (size_t)qloc * 69 + (size_t)(16 * nt + mrow)] = acc[nt][rr];
    }
  }
  if (mrow < 7) {
    #pragma unroll
    for (int rr = 0; rr < 4; ++rr)
      ex_s[16 * wv + 4 * lq + rr][mrow] = acc[4][rr];
  }
  __syncthreads();
  if (t < 64) {
    float gx, gy, gz;
    pix2qn(g_qtab.idx[qt * QT + t], gx, gy, gz);
    float swc = gx * ex_s[t][3] + gy * ex_s[t][4] + gz * ex_s[t][5];
    size_t o = pbase + (size_t)t * 69;
    part[o + 64] = ex_s[t][0];
    part[o + 65] = ex_s[t][1];
    part[o + 66] = ex_s[t][2];
    part[o + 67] = swc;
    part[o + 68] = ex_s[t][6];
  }
}

// reduce over ks planes, normalize, scatter valid pixels (out pre-zeroed by memset)
__global__ __launch_bounds__(128) void reduce_scatter_kernel(
    const float* __restrict__ part,
    float* __restrict__ out,
    int ksc)
{
  const int bq = blockIdx.x;          // b*NQP + q
  const int q  = bq % NQP;
  const int b  = bq / NQP;
  const int t  = threadIdx.x;

  const int pix = g_qtab.idx[q];
  if (pix < 0) return;                // pad query (uniform exit)

  __shared__ float pv[69];
  if (t < 69) {
    float s = 0.f;
    for (int k = 0; k < ksc; ++k)
      s += part[(size_t)k * PLANE + (size_t)bq * 69 + (size_t)t];  // coalesced
    pv[t] = s;
  }
  __syncthreads();

  const float inv = 1.0f / (pv[68] + 1e-9f);
  float val = 0.f;
  if (t == 0) {
    val = pv[67] * inv;                          // rm_cos
  } else if (t == 1) {                           // var
    #pragma unroll
    for (int i = 0; i < 3; ++i) {
      float m  = pv[61 + i] * inv;
      float sq = pv[64 + i] * inv;
      val += sq - m * m;
    }
  } else if (t < 5) {                            // qn
    float gx, gy, gz;
    pix2qn(pix, gx, gy, gz);
    val = (t == 2) ? gx : (t == 3) ? gy : gz;
  } else if (t < 69) {                           // mapped features
    val = pv[t - 5] * inv;
  }
  if (t < 69) out[(size_t)(b * 69 + t) * 4096 + pix] = val;
}

extern "C" void kernel_launch(void* const* d_in, const int* in_sizes, int n_in,
                              void* d_out, int out_size, void* d_ws, size_t ws_size,
                              hipStream_t stream) {
  const float* fea = (const float*)d_in[0];
  const float* nrm = (const float*)d_in[1];
  const float* msk = (const float*)d_in[2];
  const float* lqn = (const float*)d_in[3];
  float* part = (float*)d_ws;
  float* out  = (float*)d_out;

  hipMemsetAsync(d_out, 0, (size_t)out_size * sizeof(float), stream);

  const size_t need32 = (size_t)PLANE * 32 * sizeof(float);   // 14.70 MB
  if (ws_size >= need32) {
    partial_kernel<32><<<dim3(2 * 32 * NQT), 256, 0, stream>>>(fea, nrm, msk, lqn, part);
    reduce_scatter_kernel<<<dim3(2 * NQP), 128, 0, stream>>>(part, out, 32);
  } else {                                                    // 7.35 MB proven fit
    partial_kernel<16><<<dim3(2 * 16 * NQT), 256, 0, stream>>>(fea, nrm, msk, lqn, part);
    reduce_scatter_kernel<<<dim3(2 * NQP), 128, 0, stream>>>(part, out, 16);
  }
}